// Round 1
// baseline (4108.855 us; speedup 1.0000x reference)
//
#include <hip/hip_runtime.h>

#define B 4096
#define T 2048
#define H 64
#define NB (B / 16)   // 256 blocks, 16 batches each

typedef __attribute__((ext_vector_type(8))) short short8;
typedef __attribute__((ext_vector_type(4))) float f32x4;

__device__ __forceinline__ float sigm(float x) {
    // 1/(1+2^(-x*log2e)); x->-inf: exp2->inf, rcp->0 ; x->+inf: ->1. No NaN.
    return __builtin_amdgcn_rcpf(1.0f + exp2f(-1.4426950408889634f * x));
}
__device__ __forceinline__ float tanh_(float x) {
    float xc = fminf(15.0f, fmaxf(-15.0f, x));       // clamp so exp2 stays finite
    float e = exp2f(2.8853900817779268f * xc);       // e^(2x)
    return (e - 1.0f) * __builtin_amdgcn_rcpf(e + 1.0f);
}
__device__ __forceinline__ unsigned short f2bf(float f) {  // RNE f32->bf16
    unsigned u = __builtin_bit_cast(unsigned, f);
    u += 0x7fffu + ((u >> 16) & 1u);
    return (unsigned short)(u >> 16);
}

// ---------------------------------------------------------------------------
// Encoder: 256 blocks x 256 threads; block handles 16 batches.
// Wave w owns gate-columns u = w*16+lo across all 4 gates; B-frags (Whh) live
// in VGPRs for the whole kernel. h round-trips LDS (bf16, double-buffered).
// MFMA 16x16x32: A[m=lane&15][k=(lane>>4)*8+j], B[k][n=lane&15], D col=lane&15,
// row=(lane>>4)*4+reg  (m89/m91-verified layouts).
// ---------------------------------------------------------------------------
extern "C" __global__ void __launch_bounds__(256)
enc_kernel(const float* __restrict__ padded, const int* __restrict__ seq_len,
           const float* __restrict__ Wih, const float* __restrict__ Whh,
           const float* __restrict__ bias,
           float* __restrict__ h_out, float* __restrict__ c_out)
{
    __shared__ unsigned short hA[2][16][72];  // 72 = 64 + 8 pad (bank spread)
    __shared__ float xbuf[16][33];
    __shared__ int slen[16];

    const int tid = threadIdx.x;
    const int w = tid >> 6, L = tid & 63, lo = L & 15, hi = L >> 4;
    const int u = w * 16 + lo;          // this lane's gate column (hidden unit)
    const int b0 = blockIdx.x * 16;

    // B fragments: lane holds Whh[n = gi*64+u][k = kk*32 + hi*8 + j], j=0..7
    short8 bf[4][2];
    #pragma unroll
    for (int gi = 0; gi < 4; ++gi) {
        int row = gi * 64 + u;
        #pragma unroll
        for (int kk = 0; kk < 2; ++kk) {
            const float* src = Whh + row * 64 + kk * 32 + hi * 8;
            short8 f;
            #pragma unroll
            for (int j = 0; j < 8; ++j) f[j] = (short)f2bf(src[j]);
            bf[gi][kk] = f;
        }
    }
    float b_g[4], wi_g[4];
    #pragma unroll
    for (int gi = 0; gi < 4; ++gi) { b_g[gi] = bias[gi*64+u]; wi_g[gi] = Wih[gi*64+u]; }

    for (int i = tid; i < 2 * 16 * 72; i += 256) ((unsigned short*)hA)[i] = 0;
    if (tid < 16) slen[tid] = seq_len[b0 + tid];
    __syncthreads();

    int maxlen = 1;
    #pragma unroll
    for (int i = 0; i < 16; ++i) maxlen = max(maxlen, slen[i]);
    int len_r[4];
    #pragma unroll
    for (int r = 0; r < 4; ++r) len_r[r] = slen[hi*4 + r];

    float c_st[4] = {0,0,0,0}, h_st[4] = {0,0,0,0};

    int p = 0;
    for (int t = 0; t < maxlen; ++t) {
        if ((t & 31) == 0) {               // refill x prefetch buffer
            for (int e = tid; e < 512; e += 256) {
                int bb = e >> 5, i2 = e & 31;
                xbuf[bb][i2] = padded[(long)(b0+bb) * T + t + i2];
            }
            __syncthreads();
        }
        short8 a0 = *(const short8*)&hA[p][lo][hi*8];
        short8 a1 = *(const short8*)&hA[p][lo][32 + hi*8];
        f32x4 acc[4];
        #pragma unroll
        for (int gi = 0; gi < 4; ++gi) {
            f32x4 z = {0.f,0.f,0.f,0.f};
            z      = __builtin_amdgcn_mfma_f32_16x16x32_bf16(a0, bf[gi][0], z, 0,0,0);
            acc[gi]= __builtin_amdgcn_mfma_f32_16x16x32_bf16(a1, bf[gi][1], z, 0,0,0);
        }
        int pn = p ^ 1;
        #pragma unroll
        for (int r = 0; r < 4; ++r) {
            int bb = hi*4 + r;                       // batch slot (C row)
            float x = xbuf[bb][t & 31];
            float g0 = acc[0][r] + b_g[0] + wi_g[0]*x;   // i
            float g1 = acc[1][r] + b_g[1] + wi_g[1]*x;   // f
            float g2 = acc[2][r] + b_g[2] + wi_g[2]*x;   // g
            float g3 = acc[3][r] + b_g[3] + wi_g[3]*x;   // o
            float cn = sigm(g1) * c_st[r] + sigm(g0) * tanh_(g2);
            float hn = sigm(g3) * tanh_(cn);
            if (t < len_r[r]) { c_st[r] = cn; h_st[r] = hn; }   // mask: freeze
            hA[pn][bb][u] = f2bf(h_st[r]);
        }
        __syncthreads();
        p = pn;
    }
    #pragma unroll
    for (int r = 0; r < 4; ++r) {
        int b = b0 + hi*4 + r;
        h_out[(long)b * H + u] = h_st[r];
        c_out[(long)b * H + u] = c_st[r];
    }
}

// ---------------------------------------------------------------------------
// Bottleneck: hz = sigmoid(h @ elW.T + elb) -> out ; hd = hz @ dlW.T + dlb -> ws
// ---------------------------------------------------------------------------
extern "C" __global__ void __launch_bounds__(256)
mid_kernel(const float* __restrict__ h_enc,
           const float* __restrict__ eW, const float* __restrict__ eb,
           const float* __restrict__ dW, const float* __restrict__ db,
           float* __restrict__ hz_out, float* __restrict__ hd_out)
{
    int b = blockIdx.x * blockDim.x + threadIdx.x;
    if (b >= B) return;
    const float* h = h_enc + (long)b * H;
    float hz[3];
    #pragma unroll
    for (int j = 0; j < 3; ++j) {
        float s = eb[j];
        for (int k = 0; k < H; ++k) s += h[k] * eW[j*H + k];
        hz[j] = sigm(s);
        hz_out[b*3 + j] = hz[j];
    }
    for (int u2 = 0; u2 < H; ++u2)
        hd_out[(long)b*H + u2] = db[u2] + hz[0]*dW[u2*3] + hz[1]*dW[u2*3+1] + hz[2]*dW[u2*3+2];
}

// ---------------------------------------------------------------------------
// Decoder: same MFMA structure; x_t is the previous step's scalar y per batch
// (cross-wave reduced through LDS, double-buffered). Writes output y.
// ---------------------------------------------------------------------------
extern "C" __global__ void __launch_bounds__(256)
dec_kernel(const float* __restrict__ hd, const float* __restrict__ c_in,
           const float* __restrict__ Wih, const float* __restrict__ Whh,
           const float* __restrict__ bias, const float* __restrict__ outW,
           const float* __restrict__ outb, float* __restrict__ y_out)
{
    __shared__ unsigned short hA[2][16][72];
    __shared__ float ypart[2][16][4];

    const int tid = threadIdx.x;
    const int w = tid >> 6, L = tid & 63, lo = L & 15, hi = L >> 4;
    const int u = w * 16 + lo;
    const int b0 = blockIdx.x * 16;

    short8 bf[4][2];
    #pragma unroll
    for (int gi = 0; gi < 4; ++gi) {
        int row = gi * 64 + u;
        #pragma unroll
        for (int kk = 0; kk < 2; ++kk) {
            const float* src = Whh + row * 64 + kk * 32 + hi * 8;
            short8 f;
            #pragma unroll
            for (int j = 0; j < 8; ++j) f[j] = (short)f2bf(src[j]);
            bf[gi][kk] = f;
        }
    }
    float b_g[4], wi_g[4];
    #pragma unroll
    for (int gi = 0; gi < 4; ++gi) { b_g[gi] = bias[gi*64+u]; wi_g[gi] = Wih[gi*64+u]; }
    const float outw_u = outW[u];
    const float outb_s = outb[0];

    for (int i = tid; i < 16 * 64; i += 256) {
        int m = i >> 6, k = i & 63;
        hA[0][m][k] = f2bf(hd[(long)(b0+m)*H + k]);
    }
    float c_st[4], x_r[4] = {0,0,0,0};
    #pragma unroll
    for (int r = 0; r < 4; ++r) c_st[r] = c_in[(long)(b0 + hi*4 + r)*H + u];
    __syncthreads();

    int p = 0;
    for (int t = 0; t < T; ++t) {
        short8 a0 = *(const short8*)&hA[p][lo][hi*8];
        short8 a1 = *(const short8*)&hA[p][lo][32 + hi*8];
        f32x4 acc[4];
        #pragma unroll
        for (int gi = 0; gi < 4; ++gi) {
            f32x4 z = {0.f,0.f,0.f,0.f};
            z      = __builtin_amdgcn_mfma_f32_16x16x32_bf16(a0, bf[gi][0], z, 0,0,0);
            acc[gi]= __builtin_amdgcn_mfma_f32_16x16x32_bf16(a1, bf[gi][1], z, 0,0,0);
        }
        int pn = p ^ 1;
        float yp[4];
        #pragma unroll
        for (int r = 0; r < 4; ++r) {
            float x = x_r[r];
            float g0 = acc[0][r] + b_g[0] + wi_g[0]*x;
            float g1 = acc[1][r] + b_g[1] + wi_g[1]*x;
            float g2 = acc[2][r] + b_g[2] + wi_g[2]*x;
            float g3 = acc[3][r] + b_g[3] + wi_g[3]*x;
            float cn = sigm(g1) * c_st[r] + sigm(g0) * tanh_(g2);
            float hn = sigm(g3) * tanh_(cn);
            c_st[r] = cn;
            yp[r] = outw_u * hn;                    // partial of y over this u
            hA[pn][hi*4 + r][u] = f2bf(hn);
        }
        // reduce y over the 16 'lo' lanes (u-span of this wave)
        #pragma unroll
        for (int m = 1; m < 16; m <<= 1) {
            #pragma unroll
            for (int r = 0; r < 4; ++r) yp[r] += __shfl_xor(yp[r], m);
        }
        if (lo == 0) {
            #pragma unroll
            for (int r = 0; r < 4; ++r) ypart[t & 1][hi*4 + r][w] = yp[r];
        }
        __syncthreads();
        #pragma unroll
        for (int r = 0; r < 4; ++r) {              // cross-wave sum -> next x
            f32x4 yv = *(const f32x4*)&ypart[t & 1][hi*4 + r][0];
            x_r[r] = yv[0] + yv[1] + yv[2] + yv[3] + outb_s;
        }
        if (w == 0 && lo == 0) {
            #pragma unroll
            for (int r = 0; r < 4; ++r)
                y_out[(long)(b0 + hi*4 + r) * T + t] = x_r[r];
        }
        p = pn;
    }
}

// ---------------------------------------------------------------------------
extern "C" __global__ void __launch_bounds__(256)
loss_kernel(const float* __restrict__ padded, const float* __restrict__ y,
            const int* __restrict__ seq_len, float* __restrict__ acc2)
{
    long i0 = (long)(blockIdx.x * blockDim.x + threadIdx.x);
    long stride = (long)gridDim.x * blockDim.x;
    float s = 0.f, cnt = 0.f;
    for (long i = i0; i < (long)B * T; i += stride) {
        int b = (int)(i >> 11);              // T = 2048
        int t = (int)(i & (T - 1));
        if (t < seq_len[b]) { float d = padded[i] - y[i]; s += d * d; cnt += 1.0f; }
    }
    for (int m = 1; m < 64; m <<= 1) { s += __shfl_xor(s, m); cnt += __shfl_xor(cnt, m); }
    if ((threadIdx.x & 63) == 0) { atomicAdd(&acc2[0], s); atomicAdd(&acc2[1], cnt); }
}

extern "C" __global__ void fin_kernel(const float* __restrict__ acc2, float* __restrict__ out)
{
    out[0] = acc2[0] / acc2[1];
}

// ---------------------------------------------------------------------------
extern "C" void kernel_launch(void* const* d_in, const int* in_sizes, int n_in,
                              void* d_out, int out_size, void* d_ws, size_t ws_size,
                              hipStream_t stream)
{
    const float* padded = (const float*)d_in[0];
    const int*   seq    = (const int*)  d_in[1];
    const float* eWih   = (const float*)d_in[2];
    const float* eWhh   = (const float*)d_in[3];
    const float* eb     = (const float*)d_in[4];
    const float* elW    = (const float*)d_in[5];
    const float* elb    = (const float*)d_in[6];
    const float* dlW    = (const float*)d_in[7];
    const float* dlb    = (const float*)d_in[8];
    const float* dWih   = (const float*)d_in[9];
    const float* dWhh   = (const float*)d_in[10];
    const float* db     = (const float*)d_in[11];
    const float* outW   = (const float*)d_in[12];
    const float* outb   = (const float*)d_in[13];
    float* out = (float*)d_out;

    float* ws    = (float*)d_ws;
    float* h_enc = ws;
    float* c_enc = ws + (long)B * H;
    float* hd    = ws + 2L * B * H;
    float* acc2  = ws + 3L * B * H;

    float* out_pad = out + 1;
    float* out_y   = out + 1 + (long)B * T;
    float* out_hz  = out + 1 + 2L * (long)B * T;

    hipMemcpyAsync(out_pad, padded, (long)B * T * sizeof(float),
                   hipMemcpyDeviceToDevice, stream);
    hipMemsetAsync(acc2, 0, 2 * sizeof(float), stream);

    enc_kernel<<<NB, 256, 0, stream>>>(padded, seq, eWih, eWhh, eb, h_enc, c_enc);
    mid_kernel<<<B / 256, 256, 0, stream>>>(h_enc, elW, elb, dlW, dlb, out_hz, hd);
    dec_kernel<<<NB, 256, 0, stream>>>(hd, c_enc, dWih, dWhh, db, outW, outb, out_y);
    loss_kernel<<<1024, 256, 0, stream>>>(padded, out_y, seq, acc2);
    fin_kernel<<<1, 1, 0, stream>>>(acc2, out);
}

// Round 2
// 3213.074 us; speedup vs baseline: 1.2788x; 1.2788x over previous
//
#include <hip/hip_runtime.h>

#define B 4096
#define T 2048
#define H 64
#define NB (B / 16)   // 256 blocks, 16 batches each, 4 waves

typedef __attribute__((ext_vector_type(8))) short short8;
typedef __attribute__((ext_vector_type(4))) short short4v;
typedef __attribute__((ext_vector_type(4))) float f32x4;

__device__ __forceinline__ float sigm(float x) {
    return __builtin_amdgcn_rcpf(1.0f + exp2f(-1.4426950408889634f * x));
}
__device__ __forceinline__ float tanh_(float x) {
    float xc = fminf(15.0f, fmaxf(-15.0f, x));
    float e = exp2f(2.8853900817779268f * xc);       // e^(2x)
    return (e - 1.0f) * __builtin_amdgcn_rcpf(e + 1.0f);
}
__device__ __forceinline__ unsigned short f2bf(float f) {  // RNE f32->bf16
    unsigned u = __builtin_bit_cast(unsigned, f);
    u += 0x7fffu + ((u >> 16) & 1u);
    return (unsigned short)(u >> 16);
}

// ---------------------------------------------------------------------------
// Encoder. Swapped MFMA roles: A = Whh tile (static, regs), B = h (LDS b128).
// C: row = unit (w*16+hi*4+r), col = batch (lo). Lane writes 4 consecutive
// bf16 units of batch lo -> ds_write_b64, ~conflict-free. One barrier/step.
// x: per-lane float4 register prefetch (batch lo), no xbuf, no extra barrier.
// ---------------------------------------------------------------------------
extern "C" __global__ void __launch_bounds__(256)
enc_kernel(const float* __restrict__ padded, const int* __restrict__ seq_len,
           const float* __restrict__ Wih, const float* __restrict__ Whh,
           const float* __restrict__ bias,
           float* __restrict__ h_out, float* __restrict__ c_out)
{
    __shared__ unsigned short hA[2][16][72];  // [buf][batch][unit(64)+pad(8)]
    __shared__ int slen[16];

    const int tid = threadIdx.x;
    const int w = tid >> 6, L = tid & 63, lo = L & 15, hi = L >> 4;
    const int b0 = blockIdx.x * 16;

    // A-frags: lane holds Whh[gi*64 + w*16 + lo][kk*32 + hi*8 + j]
    short8 af[4][2];
    #pragma unroll
    for (int gi = 0; gi < 4; ++gi) {
        const int row = gi * 64 + w * 16 + lo;
        #pragma unroll
        for (int kk = 0; kk < 2; ++kk) {
            const float* src = Whh + (long)row * H + kk * 32 + hi * 8;
            short8 f;
            #pragma unroll
            for (int j = 0; j < 8; ++j) f[j] = (short)f2bf(src[j]);
            af[gi][kk] = f;
        }
    }
    float b_g[4][4], wi_g[4][4];
    #pragma unroll
    for (int gi = 0; gi < 4; ++gi)
        #pragma unroll
        for (int r = 0; r < 4; ++r) {
            const int row = gi * 64 + w * 16 + hi * 4 + r;
            b_g[gi][r] = bias[row];
            wi_g[gi][r] = Wih[row];
        }

    for (int i = tid; i < 16 * 64; i += 256) hA[0][i >> 6][i & 63] = 0;
    if (tid < 16) slen[tid] = seq_len[b0 + tid];
    __syncthreads();

    int maxlen = 1;
    #pragma unroll
    for (int i = 0; i < 16; ++i) maxlen = max(maxlen, slen[i]);
    const int len_lo = slen[lo];

    const float* xrow = padded + (long)(b0 + lo) * T;
    f32x4 xc = *(const f32x4*)(xrow);
    f32x4 xn = *(const f32x4*)(xrow + 4);

    float c_st[4] = {0,0,0,0}, h_st[4] = {0,0,0,0};

    int p = 0;
    for (int t = 0; t < maxlen; ++t) {
        const int ti = t & 3;
        if (ti == 0 && t) {                 // rotate x prefetch (4 steps ahead)
            xc = xn;
            int nb = t + 4; if (nb > T - 4) nb = T - 4;   // clamp: never consumed OOB
            xn = *(const f32x4*)(xrow + nb);
        }
        const float x = xc[ti];

        short8 hb0 = *(const short8*)&hA[p][lo][hi * 8];
        short8 hb1 = *(const short8*)&hA[p][lo][32 + hi * 8];
        f32x4 acc[4];
        #pragma unroll
        for (int gi = 0; gi < 4; ++gi) {
            f32x4 z = {b_g[gi][0], b_g[gi][1], b_g[gi][2], b_g[gi][3]};
            z = __builtin_amdgcn_mfma_f32_16x16x32_bf16(af[gi][0], hb0, z, 0,0,0);
            acc[gi] = __builtin_amdgcn_mfma_f32_16x16x32_bf16(af[gi][1], hb1, z, 0,0,0);
        }
        const int pn = p ^ 1;
        const bool act = t < len_lo;
        short4v hp;
        #pragma unroll
        for (int r = 0; r < 4; ++r) {
            float g0 = acc[0][r] + wi_g[0][r] * x;   // i
            float g1 = acc[1][r] + wi_g[1][r] * x;   // f
            float g2 = acc[2][r] + wi_g[2][r] * x;   // g
            float g3 = acc[3][r] + wi_g[3][r] * x;   // o
            float cn = sigm(g1) * c_st[r] + sigm(g0) * tanh_(g2);
            float hn = sigm(g3) * tanh_(cn);
            if (act) { c_st[r] = cn; h_st[r] = hn; }
            hp[r] = (short)f2bf(h_st[r]);
        }
        *(short4v*)&hA[pn][lo][w * 16 + hi * 4] = hp;   // ds_write_b64
        __syncthreads();
        p = pn;
    }
    f32x4 hv = {h_st[0], h_st[1], h_st[2], h_st[3]};
    f32x4 cv = {c_st[0], c_st[1], c_st[2], c_st[3]};
    *(f32x4*)&h_out[(long)(b0 + lo) * H + w * 16 + hi * 4] = hv;
    *(f32x4*)&c_out[(long)(b0 + lo) * H + w * 16 + hi * 4] = cv;
}

// ---------------------------------------------------------------------------
// Bottleneck + y0 correction: hz = sigmoid(h@elW.T+elb) -> out;
// hd = hz@dlW.T+dlb -> ws; y0c = outW.hd + outb -> ws (decoder t=0 fixup).
// ---------------------------------------------------------------------------
extern "C" __global__ void __launch_bounds__(256)
mid_kernel(const float* __restrict__ h_enc,
           const float* __restrict__ eW, const float* __restrict__ eb,
           const float* __restrict__ dW, const float* __restrict__ db,
           const float* __restrict__ outW, const float* __restrict__ outb,
           float* __restrict__ hz_out, float* __restrict__ hd_out,
           float* __restrict__ y0c)
{
    int b = blockIdx.x * blockDim.x + threadIdx.x;
    if (b >= B) return;
    const float* h = h_enc + (long)b * H;
    float hz[3];
    #pragma unroll
    for (int j = 0; j < 3; ++j) {
        float s = eb[j];
        for (int k = 0; k < H; ++k) s += h[k] * eW[j*H + k];
        hz[j] = sigm(s);
        hz_out[b*3 + j] = hz[j];
    }
    float y0 = outb[0];
    for (int u = 0; u < H; ++u) {
        float hd = db[u] + hz[0]*dW[u*3] + hz[1]*dW[u*3+1] + hz[2]*dW[u*3+2];
        hd_out[(long)b*H + u] = hd;
        y0 += outW[u] * hd;
    }
    y0c[b] = y0;
}

// ---------------------------------------------------------------------------
// Decoder with rank-1 fold: W' = Whh + Wih (x) outW, b' = b + Wih*outb.
// Pure LSTM recurrence, no x feedback. y_{t-1} recovered via 2 extra MFMAs
// on wave 0 (A row 0 = outW), stored off the critical path. t=0 gate fixup
// subtracts Wih*y0c (since x_0 = 0, not y_{-1}).
// ---------------------------------------------------------------------------
extern "C" __global__ void __launch_bounds__(256)
dec_kernel(const float* __restrict__ hd, const float* __restrict__ c_in,
           const float* __restrict__ Wih, const float* __restrict__ Whh,
           const float* __restrict__ bias, const float* __restrict__ outW,
           const float* __restrict__ outb, const float* __restrict__ y0c,
           float* __restrict__ y_out)
{
    __shared__ unsigned short hA[2][16][72];

    const int tid = threadIdx.x;
    const int w = tid >> 6, L = tid & 63, lo = L & 15, hi = L >> 4;
    const int b0 = blockIdx.x * 16;

    // A-frags of W'
    short8 af[4][2];
    #pragma unroll
    for (int gi = 0; gi < 4; ++gi) {
        const int row = gi * 64 + w * 16 + lo;
        const float wir = Wih[row];
        #pragma unroll
        for (int kk = 0; kk < 2; ++kk) {
            const float* src = Whh + (long)row * H + kk * 32 + hi * 8;
            const float* ow  = outW + kk * 32 + hi * 8;
            short8 f;
            #pragma unroll
            for (int j = 0; j < 8; ++j) f[j] = (short)f2bf(src[j] + wir * ow[j]);
            af[gi][kk] = f;
        }
    }
    const float outb_s = outb[0];
    const float y0 = y0c[b0 + lo];
    float b_g[4][4], corr[4][4];
    #pragma unroll
    for (int gi = 0; gi < 4; ++gi)
        #pragma unroll
        for (int r = 0; r < 4; ++r) {
            const int row = gi * 64 + w * 16 + hi * 4 + r;
            const float wir = Wih[row];
            b_g[gi][r] = bias[row] + wir * outb_s;
            corr[gi][r] = wir * y0;           // subtract at t==0 only
        }
    // y-extraction frag (wave 0): A row 0 = outW, rest 0
    short8 ya[2] = { (short8)0, (short8)0 };
    if (w == 0 && lo == 0) {
        #pragma unroll
        for (int kk = 0; kk < 2; ++kk) {
            short8 f;
            #pragma unroll
            for (int j = 0; j < 8; ++j) f[j] = (short)f2bf(outW[kk*32 + hi*8 + j]);
            ya[kk] = f;
        }
    }

    for (int i = tid; i < 16 * 64; i += 256) {
        int m = i >> 6, k = i & 63;
        hA[0][m][k] = f2bf(hd[(long)(b0 + m) * H + k]);
    }
    float c_st[4];
    {
        f32x4 cv = *(const f32x4*)&c_in[(long)(b0 + lo) * H + w * 16 + hi * 4];
        #pragma unroll
        for (int r = 0; r < 4; ++r) c_st[r] = cv[r];
    }
    __syncthreads();

    int p = 0;
    for (int t = 0; t < T; ++t) {
        short8 hb0 = *(const short8*)&hA[p][lo][hi * 8];
        short8 hb1 = *(const short8*)&hA[p][lo][32 + hi * 8];
        f32x4 acc[4];
        #pragma unroll
        for (int gi = 0; gi < 4; ++gi) {
            f32x4 z = {b_g[gi][0], b_g[gi][1], b_g[gi][2], b_g[gi][3]};
            z = __builtin_amdgcn_mfma_f32_16x16x32_bf16(af[gi][0], hb0, z, 0,0,0);
            acc[gi] = __builtin_amdgcn_mfma_f32_16x16x32_bf16(af[gi][1], hb1, z, 0,0,0);
        }
        if (w == 0) {   // y_{t-1} = outW . h_{t-1} + outb  (off critical path)
            f32x4 zy = {outb_s, outb_s, outb_s, outb_s};
            zy = __builtin_amdgcn_mfma_f32_16x16x32_bf16(ya[0], hb0, zy, 0,0,0);
            zy = __builtin_amdgcn_mfma_f32_16x16x32_bf16(ya[1], hb1, zy, 0,0,0);
            if (hi == 0 && t > 0) y_out[(long)(b0 + lo) * T + (t - 1)] = zy[0];
        }
        if (t == 0) {   // x_0 = 0, not y_{-1}: undo the folded rank-1 term
            #pragma unroll
            for (int gi = 0; gi < 4; ++gi)
                #pragma unroll
                for (int r = 0; r < 4; ++r) acc[gi][r] -= corr[gi][r];
        }
        const int pn = p ^ 1;
        short4v hp;
        #pragma unroll
        for (int r = 0; r < 4; ++r) {
            float cn = sigm(acc[1][r]) * c_st[r] + sigm(acc[0][r]) * tanh_(acc[2][r]);
            float hn = sigm(acc[3][r]) * tanh_(cn);
            c_st[r] = cn;
            hp[r] = (short)f2bf(hn);
        }
        *(short4v*)&hA[pn][lo][w * 16 + hi * 4] = hp;
        __syncthreads();
        p = pn;
    }
    if (w == 0) {       // final y_{T-1}
        short8 hb0 = *(const short8*)&hA[p][lo][hi * 8];
        short8 hb1 = *(const short8*)&hA[p][lo][32 + hi * 8];
        f32x4 zy = {outb_s, outb_s, outb_s, outb_s};
        zy = __builtin_amdgcn_mfma_f32_16x16x32_bf16(ya[0], hb0, zy, 0,0,0);
        zy = __builtin_amdgcn_mfma_f32_16x16x32_bf16(ya[1], hb1, zy, 0,0,0);
        if (hi == 0) y_out[(long)(b0 + lo) * T + (T - 1)] = zy[0];
    }
}

// ---------------------------------------------------------------------------
extern "C" __global__ void __launch_bounds__(256)
loss_kernel(const float* __restrict__ padded, const float* __restrict__ y,
            const int* __restrict__ seq_len, float* __restrict__ acc2)
{
    long i0 = (long)(blockIdx.x * blockDim.x + threadIdx.x);
    long stride = (long)gridDim.x * blockDim.x;
    float s = 0.f, cnt = 0.f;
    for (long i = i0; i < (long)B * T; i += stride) {
        int b = (int)(i >> 11);
        int t = (int)(i & (T - 1));
        if (t < seq_len[b]) { float d = padded[i] - y[i]; s += d * d; cnt += 1.0f; }
    }
    for (int m = 1; m < 64; m <<= 1) { s += __shfl_xor(s, m); cnt += __shfl_xor(cnt, m); }
    if ((threadIdx.x & 63) == 0) { atomicAdd(&acc2[0], s); atomicAdd(&acc2[1], cnt); }
}

extern "C" __global__ void fin_kernel(const float* __restrict__ acc2, float* __restrict__ out)
{
    out[0] = acc2[0] / acc2[1];
}

// ---------------------------------------------------------------------------
extern "C" void kernel_launch(void* const* d_in, const int* in_sizes, int n_in,
                              void* d_out, int out_size, void* d_ws, size_t ws_size,
                              hipStream_t stream)
{
    const float* padded = (const float*)d_in[0];
    const int*   seq    = (const int*)  d_in[1];
    const float* eWih   = (const float*)d_in[2];
    const float* eWhh   = (const float*)d_in[3];
    const float* eb     = (const float*)d_in[4];
    const float* elW    = (const float*)d_in[5];
    const float* elb    = (const float*)d_in[6];
    const float* dlW    = (const float*)d_in[7];
    const float* dlb    = (const float*)d_in[8];
    const float* dWih   = (const float*)d_in[9];
    const float* dWhh   = (const float*)d_in[10];
    const float* db     = (const float*)d_in[11];
    const float* outW   = (const float*)d_in[12];
    const float* outb   = (const float*)d_in[13];
    float* out = (float*)d_out;

    float* ws    = (float*)d_ws;
    float* h_enc = ws;
    float* c_enc = ws + (long)B * H;
    float* hd    = ws + 2L * B * H;
    float* y0c   = ws + 3L * B * H;
    float* acc2  = ws + 3L * B * H + B;

    float* out_pad = out + 1;
    float* out_y   = out + 1 + (long)B * T;
    float* out_hz  = out + 1 + 2L * (long)B * T;

    hipMemcpyAsync(out_pad, padded, (long)B * T * sizeof(float),
                   hipMemcpyDeviceToDevice, stream);
    hipMemsetAsync(acc2, 0, 2 * sizeof(float), stream);

    enc_kernel<<<NB, 256, 0, stream>>>(padded, seq, eWih, eWhh, eb, h_enc, c_enc);
    mid_kernel<<<B / 256, 256, 0, stream>>>(h_enc, elW, elb, dlW, dlb, outW, outb,
                                            out_hz, hd, y0c);
    dec_kernel<<<NB, 256, 0, stream>>>(hd, c_enc, dWih, dWhh, db, outW, outb, y0c, out_y);
    loss_kernel<<<1024, 256, 0, stream>>>(padded, out_y, seq, acc2);
    fin_kernel<<<1, 1, 0, stream>>>(acc2, out);
}